// Round 3
// baseline (981.696 us; speedup 1.0000x reference)
//
#include <hip/hip_runtime.h>
#include <math.h>

// Problem constants (p_sample=100 fixed by setup_inputs -> T = 101)
#define NB_B   512
#define NK     256
#define NKH    128
#define NG3    384
#define NT     101
#define NF     16
#define NPASS  (512ull*256*256)   // 33,554,432 elements per passthrough tensor

// ---- workspace layout (float offsets) ----
#define OFF_GX   0ull
#define N_GX     (512ull*101*384)        // 19,857,408
#define OFF_CT   (OFF_GX + N_GX)         // c_t: 512*128
#define OFF_ENC  (OFF_CT + 512ull*128)   // enc: 16*512*256
#define OFF_PRED (OFF_ENC + 16ull*512*256)
#define OFF_TOT  (OFF_PRED + 16ull*512*256)  // totals: 16*512*512
#define OFF_LSE  (OFF_TOT + 16ull*512*512)   // 8192
#define OFF_DML  (OFF_LSE + 8192ull)         // 8192 (diag - lse per row)
#define OFF_WT   (OFF_DML + 8192ull)         // W_ih^T: 256*384
#define OFF_WKT  (OFF_WT + 384ull*256)       // Wk_w transposed: 16*128*256
#define OFF_CNT  (OFF_WKT + 16ull*128*256)   // 1 int (correct count)
// total ~115.8 MB of d_ws

// Transpose W_ih -> Wt[k][g], Wk_w[f][k][h] -> Wkt[f][h][k]; also zero cnt.
__global__ __launch_bounds__(256) void k_transpose(
    const float* __restrict__ W_ih, const float* __restrict__ Wk_w,
    float* __restrict__ Wt, float* __restrict__ Wkt, int* __restrict__ cnt) {
  int idx = blockIdx.x * 256 + threadIdx.x;
  if (idx == 0) *cnt = 0;
  if (idx < 384 * 256) {
    int g = idx % 384, k = idx / 384;
    Wt[idx] = W_ih[g * 256 + k];
  }
  if (idx < 16 * 128 * 256) {
    int k = idx & 255, h = (idx >> 8) & 127, f = idx >> 15;
    Wkt[idx] = Wk_w[(f * 256 + k) * 128 + h];
  }
}

// gx[t][b][g] = b_ih[g] + sum_k zq[b][k][t] * W_ih[g][k]
// one block per b; X (256k x 101t) staged in LDS in 64-k chunks; t contiguous.
__global__ __launch_bounds__(768) void k_gx(
    const float* __restrict__ zq, const float* __restrict__ Wt,
    const float* __restrict__ b_ih, float* __restrict__ gx) {
  __shared__ float Xs[64][104];
  int b = blockIdx.x;
  int tid = threadIdx.x;
  int g = tid % 384;
  int th = tid / 384;           // t-half: 0 -> t 0..51, 1 -> t 52..103
  int lane = tid & 63, wid = tid >> 6;  // 12 waves
  float acc[52];
#pragma unroll
  for (int i = 0; i < 52; i++) acc[i] = 0.f;
  const float* zb = zq + (size_t)b * 65536;
  for (int kc = 0; kc < 4; kc++) {
    __syncthreads();
    for (int k = wid; k < 64; k += 12) {
      int kk = kc * 64 + k;
      Xs[k][lane] = zb[kk * 256 + lane];
      int t1 = 64 + lane;
      if (t1 < 104) Xs[k][t1] = (t1 < 101) ? zb[kk * 256 + t1] : 0.f;
    }
    __syncthreads();
    for (int k = 0; k < 64; k++) {
      float w = Wt[(kc * 64 + k) * 384 + g];       // coalesced (g contiguous)
      const float4* xp = (const float4*)&Xs[k][th * 52];  // wave-broadcast
#pragma unroll
      for (int i = 0; i < 13; i++) {
        float4 x = xp[i];
        acc[4 * i + 0] += w * x.x;
        acc[4 * i + 1] += w * x.y;
        acc[4 * i + 2] += w * x.z;
        acc[4 * i + 3] += w * x.w;
      }
    }
  }
  float bias = b_ih[g];
  int t0 = th * 52;
#pragma unroll
  for (int i = 0; i < 52; i++) {
    int t = t0 + i;
    if (t < 101) gx[(size_t)t * (512 * 384) + b * 384 + g] = acc[i] + bias;
  }
}

// GRU scan fused with passthrough copy (block specialization).
// Blocks 0..255: scan role — 2 batch rows per block, 101 sequential steps.
//   thread = (g in 0..383, kh in {0,1}); W_hh[g][kh*64..+63] in 16 float4 regs.
//   Latency/barrier-bound, ~1 block/CU, 12 waves — leaves >4 TB/s HBM idle.
// Blocks 256..511: copy role — grid-stride copy of the two passthrough
//   tensors. Sources are 256B-aligned -> float4 loads; dst is out+2 (8B
//   aligned only) -> paired float2 stores. Co-resident with scan blocks
//   (12+12=24 waves/CU), soaking the idle bandwidth.
__global__ __launch_bounds__(768) void k_scan(
    const float* __restrict__ gx, const float* __restrict__ W_hh,
    const float* __restrict__ b_hh, const float* __restrict__ hidden,
    float* __restrict__ ct,
    const float* __restrict__ src0, const float* __restrict__ src1,
    float2* __restrict__ d0, float2* __restrict__ d1) {
  int tid = threadIdx.x;
  if (blockIdx.x >= 256) {
    const float4* S0 = (const float4*)src0;
    const float4* S1 = (const float4*)src1;
    const size_t n4 = NPASS / 4;  // 8,388,608 float4 per tensor
    const size_t stride = 256ull * 768;
    for (size_t i = (size_t)(blockIdx.x - 256) * 768 + tid; i < n4; i += stride) {
      float4 a = S0[i];
      float4 b = S1[i];
      d0[2 * i]     = make_float2(a.x, a.y);
      d0[2 * i + 1] = make_float2(a.z, a.w);
      d1[2 * i]     = make_float2(b.x, b.y);
      d1[2 * i + 1] = make_float2(b.z, b.w);
    }
    return;
  }
  __shared__ float hs[2][128];
  __shared__ float ghp[2][2][384];  // [row][k-half][g]
  int b0 = blockIdx.x * 2;
  int g = tid % 384, kh = tid / 384;
  float4 w[16];
  const float4* wp = (const float4*)(W_hh + g * 128 + kh * 64);
#pragma unroll
  for (int i = 0; i < 16; i++) w[i] = wp[i];
  if (tid < 256) {
    int r = tid >> 7, k = tid & 127;
    hs[r][k] = hidden[(b0 + r) * 128 + k];
  }
  __syncthreads();
  for (int t = 0; t < 101; t++) {
    const float4* h0 = (const float4*)&hs[0][kh * 64];
    const float4* h1 = (const float4*)&hs[1][kh * 64];
    float a0 = 0.f, a1 = 0.f;
#pragma unroll
    for (int i = 0; i < 16; i++) {
      float4 wv = w[i], x0 = h0[i], x1 = h1[i];
      a0 += wv.x * x0.x + wv.y * x0.y + wv.z * x0.z + wv.w * x0.w;
      a1 += wv.x * x1.x + wv.y * x1.y + wv.z * x1.z + wv.w * x1.w;
    }
    ghp[0][kh][g] = a0;
    ghp[1][kh][g] = a1;
    __syncthreads();
    if (tid < 256) {
      int r = tid >> 7, k = tid & 127;
      const float* gxb = gx + (size_t)t * (512 * 384) + (b0 + r) * 384;
      float xr = gxb[k], xz = gxb[128 + k], xn = gxb[256 + k];
      float hr = ghp[r][0][k] + ghp[r][1][k] + b_hh[k];
      float hz = ghp[r][0][128 + k] + ghp[r][1][128 + k] + b_hh[128 + k];
      float hn = ghp[r][0][256 + k] + ghp[r][1][256 + k] + b_hh[256 + k];
      float rr = 1.f / (1.f + __expf(-(xr + hr)));
      float zz = 1.f / (1.f + __expf(-(xz + hz)));
      float nn = tanhf(xn + rr * hn);
      hs[r][k] = (1.f - zz) * nn + zz * hs[r][k];
    }
    __syncthreads();
  }
  if (tid < 256) {
    int r = tid >> 7, k = tid & 127;
    ct[(b0 + r) * 128 + k] = hs[r][k];
  }
}

// enc[f][b][k] = zq[b][k][101+f]  (LDS bounce to coalesce both sides)
__global__ __launch_bounds__(256) void k_enc(const float* __restrict__ zq,
                                             float* __restrict__ enc) {
  __shared__ float tile[256][17];
  int b = blockIdx.x, tid = threadIdx.x;
  const float* zb = zq + (size_t)b * 65536;
  for (int pass = 0; pass < 16; pass++) {
    int idx = pass * 256 + tid;
    int k = idx >> 4, f = idx & 15;
    tile[k][f] = zb[k * 256 + 101 + f];
  }
  __syncthreads();
  for (int f = 0; f < 16; f++)
    enc[(size_t)f * 131072 + b * 256 + tid] = tile[tid][f];
}

// pred[f][c][k] = Wk_b[f][k] + sum_h Wkt[f][h][k] * ct[c][h]
__global__ __launch_bounds__(256) void k_pred(
    const float* __restrict__ Wkt, const float* __restrict__ Wk_b,
    const float* __restrict__ ct, float* __restrict__ pred) {
  __shared__ float cts[32][128];
  int f = blockIdx.x, c0 = blockIdx.y * 32;
  int tid = threadIdx.x;  // = k
  for (int pass = 0; pass < 16; pass++) {
    int idx = pass * 256 + tid;
    int cc = idx >> 7, h = idx & 127;
    cts[cc][h] = ct[(c0 + cc) * 128 + h];
  }
  __syncthreads();
  float acc[32];
#pragma unroll
  for (int i = 0; i < 32; i++) acc[i] = 0.f;
  const float* wb = Wkt + (size_t)f * 32768 + tid;
  for (int h = 0; h < 128; h += 4) {
    float w0 = wb[(h + 0) * 256], w1 = wb[(h + 1) * 256];
    float w2 = wb[(h + 2) * 256], w3 = wb[(h + 3) * 256];
#pragma unroll
    for (int cc = 0; cc < 32; cc++) {
      float4 cv = *(const float4*)&cts[cc][h];
      acc[cc] += w0 * cv.x + w1 * cv.y + w2 * cv.z + w3 * cv.w;
    }
  }
  float bias = Wk_b[f * 256 + tid];
#pragma unroll
  for (int cc = 0; cc < 32; cc++)
    pred[((size_t)f * 512 + c0 + cc) * 256 + tid] = acc[cc] + bias;
}

// totals[f][b][c] = sum_k enc[f][b][k] * pred[f][c][k]; 64x64 tiles, K=256
__global__ __launch_bounds__(256) void k_totals(
    const float* __restrict__ enc, const float* __restrict__ pred,
    float* __restrict__ tot) {
  __shared__ float As[32][68];
  __shared__ float Bs[32][68];
  int f = blockIdx.z, b0 = blockIdx.y * 64, c0 = blockIdx.x * 64;
  int tid = threadIdx.x;
  int tx = tid & 15, ty = tid >> 4;
  float acc[4][4];
#pragma unroll
  for (int i = 0; i < 4; i++)
#pragma unroll
    for (int j = 0; j < 4; j++) acc[i][j] = 0.f;
  const float* Ab = enc + (size_t)f * 131072;
  const float* Bb = pred + (size_t)f * 131072;
  int lr = tid >> 3;        // 0..31
  int lc = (tid & 7) * 4;   // k sub-offset
  for (int kc = 0; kc < 8; kc++) {
    int k0 = kc * 32;
    __syncthreads();
    float4 av0 = *(const float4*)&Ab[(b0 + lr) * 256 + k0 + lc];
    float4 av1 = *(const float4*)&Ab[(b0 + 32 + lr) * 256 + k0 + lc];
    float4 bv0 = *(const float4*)&Bb[(c0 + lr) * 256 + k0 + lc];
    float4 bv1 = *(const float4*)&Bb[(c0 + 32 + lr) * 256 + k0 + lc];
    As[lc + 0][lr] = av0.x; As[lc + 1][lr] = av0.y;
    As[lc + 2][lr] = av0.z; As[lc + 3][lr] = av0.w;
    As[lc + 0][lr + 32] = av1.x; As[lc + 1][lr + 32] = av1.y;
    As[lc + 2][lr + 32] = av1.z; As[lc + 3][lr + 32] = av1.w;
    Bs[lc + 0][lr] = bv0.x; Bs[lc + 1][lr] = bv0.y;
    Bs[lc + 2][lr] = bv0.z; Bs[lc + 3][lr] = bv0.w;
    Bs[lc + 0][lr + 32] = bv1.x; Bs[lc + 1][lr + 32] = bv1.y;
    Bs[lc + 2][lr + 32] = bv1.z; Bs[lc + 3][lr + 32] = bv1.w;
    __syncthreads();
#pragma unroll
    for (int kk = 0; kk < 32; kk++) {
      float4 a = *(const float4*)&As[kk][ty * 4];
      float4 bq = *(const float4*)&Bs[kk][tx * 4];
      acc[0][0] += a.x * bq.x; acc[0][1] += a.x * bq.y;
      acc[0][2] += a.x * bq.z; acc[0][3] += a.x * bq.w;
      acc[1][0] += a.y * bq.x; acc[1][1] += a.y * bq.y;
      acc[1][2] += a.y * bq.z; acc[1][3] += a.y * bq.w;
      acc[2][0] += a.z * bq.x; acc[2][1] += a.z * bq.y;
      acc[2][2] += a.z * bq.z; acc[2][3] += a.z * bq.w;
      acc[3][0] += a.w * bq.x; acc[3][1] += a.w * bq.y;
      acc[3][2] += a.w * bq.z; acc[3][3] += a.w * bq.w;
    }
  }
#pragma unroll
  for (int i = 0; i < 4; i++) {
    float4 v = make_float4(acc[i][0], acc[i][1], acc[i][2], acc[i][3]);
    *(float4*)&tot[(size_t)f * 262144 + (b0 + ty * 4 + i) * 512 + c0 + tx * 4] = v;
  }
}

// per-row logsumexp + (diag - lse); one wave per (f,b) row
__global__ __launch_bounds__(64) void k_lse(const float* __restrict__ tot,
                                            float* __restrict__ lse,
                                            float* __restrict__ dml) {
  int row = blockIdx.x;  // f*512 + b
  int b = row & 511;
  int lane = threadIdx.x;
  const float* tr = tot + (size_t)row * 512;
  float v[8];
  float mx = -1e30f;
#pragma unroll
  for (int i = 0; i < 8; i++) { v[i] = tr[i * 64 + lane]; mx = fmaxf(mx, v[i]); }
#pragma unroll
  for (int s = 32; s > 0; s >>= 1) mx = fmaxf(mx, __shfl_xor(mx, s));
  float sum = 0.f;
#pragma unroll
  for (int i = 0; i < 8; i++) sum += __expf(v[i] - mx);
#pragma unroll
  for (int s = 32; s > 0; s >>= 1) sum += __shfl_xor(sum, s);
  if (lane == 0) {
    float l = __logf(sum) + mx;
    lse[row] = l;
    dml[row] = tr[b] - l;
  }
}

// accuracy: preds_idx[c] = argmax_b (totals[15][b][c] - lse15[b]); first-max tiebreak
__global__ __launch_bounds__(64) void k_acc(const float* __restrict__ tot,
                                            const float* __restrict__ lse,
                                            int* __restrict__ cnt) {
  int c = blockIdx.x * 64 + threadIdx.x;
  const float* t15 = tot + (size_t)15 * 262144;
  const float* l15 = lse + 15 * 512;
  float best = -1e30f;
  int bi = 0;
  for (int b = 0; b < 512; b++) {
    float v = t15[(size_t)b * 512 + c] - l15[b];
    if (v > best) { best = v; bi = b; }
  }
  if (bi == c) atomicAdd(cnt, 1);
}

__global__ __launch_bounds__(256) void k_fin(const float* __restrict__ dml,
                                             const int* __restrict__ cnt,
                                             float* __restrict__ out) {
  __shared__ float red[256];
  int tid = threadIdx.x;
  float s = 0.f;
  for (int i = tid; i < 8192; i += 256) s += dml[i];
  red[tid] = s;
  __syncthreads();
  for (int st = 128; st > 0; st >>= 1) {
    if (tid < st) red[tid] += red[tid + st];
    __syncthreads();
  }
  if (tid == 0) {
    out[1] = -red[0] / 8192.f;            // nce
    out[0] = (float)(*cnt) / 512.f;       // accuracy
  }
}

extern "C" void kernel_launch(void* const* d_in, const int* in_sizes, int n_in,
                              void* d_out, int out_size, void* d_ws, size_t ws_size,
                              hipStream_t stream) {
  const float* zq   = (const float*)d_in[0];   // z_q_x_st
  const float* ze   = (const float*)d_in[1];   // z_e_x (passthrough)
  const float* zqx  = (const float*)d_in[2];   // z_q_x (passthrough)
  const float* hid  = (const float*)d_in[3];   // hidden (1,B,KH)
  const float* W_ih = (const float*)d_in[4];
  const float* W_hh = (const float*)d_in[5];
  const float* b_ih = (const float*)d_in[6];
  const float* b_hh = (const float*)d_in[7];
  const float* Wk_w = (const float*)d_in[8];
  const float* Wk_b = (const float*)d_in[9];
  // d_in[10] = p_sample (always 100 per setup_inputs; T=101 baked in)
  float* out = (float*)d_out;
  float* ws  = (float*)d_ws;   // needs ~116 MB

  k_transpose<<<2048, 256, 0, stream>>>(W_ih, Wk_w, ws + OFF_WT, ws + OFF_WKT,
                                        (int*)(ws + OFF_CNT));
  k_gx<<<512, 768, 0, stream>>>(zq, ws + OFF_WT, b_ih, ws + OFF_GX);
  // scan (blocks 0..255) + passthrough copy (blocks 256..511) fused:
  // copy soaks the HBM bandwidth the barrier-bound scan leaves idle.
  k_scan<<<512, 768, 0, stream>>>(ws + OFF_GX, W_hh, b_hh, hid, ws + OFF_CT,
                                  ze, zqx,
                                  (float2*)(out + 2), (float2*)(out + 2 + NPASS));
  k_enc<<<512, 256, 0, stream>>>(zq, ws + OFF_ENC);
  k_pred<<<dim3(16, 16), 256, 0, stream>>>(ws + OFF_WKT, Wk_b, ws + OFF_CT, ws + OFF_PRED);
  k_totals<<<dim3(8, 8, 16), 256, 0, stream>>>(ws + OFF_ENC, ws + OFF_PRED, ws + OFF_TOT);
  k_lse<<<8192, 64, 0, stream>>>(ws + OFF_TOT, ws + OFF_LSE, ws + OFF_DML);
  k_acc<<<8, 64, 0, stream>>>(ws + OFF_TOT, ws + OFF_LSE, (int*)(ws + OFF_CNT));
  k_fin<<<1, 256, 0, stream>>>(ws + OFF_DML, (const int*)(ws + OFF_CNT), out);
}

// Round 5
// 913.478 us; speedup vs baseline: 1.0747x; 1.0747x over previous
//
#include <hip/hip_runtime.h>
#include <math.h>

// Problem constants (p_sample=100 fixed by setup_inputs -> T = 101)
#define NB_B   512
#define NK     256
#define NKH    128
#define NG3    384
#define NT     101
#define NF     16
#define NPASS  (512ull*256*256)   // 33,554,432 elements per passthrough tensor

// ---- workspace layout (float offsets) ----
#define OFF_GX   0ull
#define N_GX     (512ull*101*384)        // 19,857,408
#define OFF_CT   (OFF_GX + N_GX)         // c_t: 512*128
#define OFF_ENC  (OFF_CT + 512ull*128)   // enc: 16*512*256
#define OFF_PRED (OFF_ENC + 16ull*512*256)
#define OFF_TOT  (OFF_PRED + 16ull*512*256)  // totals: 16*512*512
#define OFF_LSE  (OFF_TOT + 16ull*512*512)   // 8192
#define OFF_DML  (OFF_LSE + 8192ull)         // 8192 (diag - lse per row)
#define OFF_WT   (OFF_DML + 8192ull)         // W_ih^T: 256*384
#define OFF_WKT  (OFF_WT + 384ull*256)       // Wk_w transposed: 16*128*256
#define OFF_CNT  (OFF_WKT + 16ull*128*256)   // 1 int (correct count)
// total ~115.8 MB of d_ws

// Transpose W_ih -> Wt[k][g], Wk_w[f][k][h] -> Wkt[f][h][k]; also zero cnt.
__global__ __launch_bounds__(256) void k_transpose(
    const float* __restrict__ W_ih, const float* __restrict__ Wk_w,
    float* __restrict__ Wt, float* __restrict__ Wkt, int* __restrict__ cnt) {
  int idx = blockIdx.x * 256 + threadIdx.x;
  if (idx == 0) *cnt = 0;
  if (idx < 384 * 256) {
    int g = idx % 384, k = idx / 384;
    Wt[idx] = W_ih[g * 256 + k];
  }
  if (idx < 16 * 128 * 256) {
    int k = idx & 255, h = (idx >> 8) & 127, f = idx >> 15;
    Wkt[idx] = Wk_w[(f * 256 + k) * 128 + h];
  }
}

// gx[t][b][g] = b_ih[g] + sum_k zq[b][k][t] * W_ih[g][k]
// one block per b. Register tile: 4 g x 13 t per thread (768 thr = 96 gquad x 8 ttile).
// Per 32-k chunk: X (32x104) and W (32x384) staged in LDS.
// Inner loop per k: 1 ds_read_b128 (W quad) + 13 ds_read_b32 broadcast (X) + 52 FMA
//   -> ~87 LDS-cyc vs 104 VALU-cyc: VALU-bound (old layout was 13 b128 = 156 cyc, LDS-bound).
__global__ __launch_bounds__(768) void k_gx(
    const float* __restrict__ zq, const float* __restrict__ Wt,
    const float* __restrict__ b_ih, float* __restrict__ gx) {
  __shared__ float Xs[32][104];      // 13,312 B
  __shared__ float Ws[32 * 384];     // 49,152 B  (total 62,464 B < 64 KB)
  int b = blockIdx.x;
  int tid = threadIdx.x;
  int q = tid % 96;                  // g-quad: g0 = 4q
  int tt = tid / 96;                 // 0..7 -> t0 = 13*tt (covers 104, pad cols 101..103 = 0)
  int g0 = q * 4;
  int t0 = tt * 13;
  int lane = tid & 63, wid = tid >> 6;  // 12 waves
  float acc[4][13];
#pragma unroll
  for (int i = 0; i < 4; i++)
#pragma unroll
    for (int j = 0; j < 13; j++) acc[i][j] = 0.f;
  const float* zb = zq + (size_t)b * 65536;
  for (int kc = 0; kc < 8; kc++) {
    __syncthreads();
    // stage X rows kc*32 .. +31 (t contiguous; cols 101..103 zero-padded)
    for (int k = wid; k < 32; k += 12) {
      int kk = kc * 32 + k;
      Xs[k][lane] = zb[kk * 256 + lane];
      int t1 = 64 + lane;
      if (t1 < 104) Xs[k][t1] = (t1 < 101) ? zb[kk * 256 + t1] : 0.f;
    }
    // stage W rows: Ws[k*384+g] = Wt[(kc*32+k)*384+g]; 12288 floats as 3072 float4
    {
      const float4* wsrc = (const float4*)(Wt + (size_t)kc * 32 * 384);
      float4* wdst = (float4*)Ws;
      for (int i = tid; i < 3072; i += 768) wdst[i] = wsrc[i];
    }
    __syncthreads();
    for (int k = 0; k < 32; k++) {
      float4 w = *(const float4*)&Ws[k * 384 + g0];   // stride-16B across lanes: full-BW
      const float* xr = &Xs[k][t0];                   // wave-broadcast (1-2 addr groups)
#pragma unroll
      for (int j = 0; j < 13; j++) {
        float x = xr[j];
        acc[0][j] += w.x * x;
        acc[1][j] += w.y * x;
        acc[2][j] += w.z * x;
        acc[3][j] += w.w * x;
      }
    }
  }
  float4 bias = *(const float4*)&b_ih[g0];
#pragma unroll
  for (int j = 0; j < 13; j++) {
    int t = t0 + j;
    if (t < 101) {
      float4 v = make_float4(acc[0][j] + bias.x, acc[1][j] + bias.y,
                             acc[2][j] + bias.z, acc[3][j] + bias.w);
      *(float4*)&gx[(size_t)t * (512 * 384) + b * 384 + g0] = v;
    }
  }
}

// GRU scan fused with passthrough copy (block specialization).
// Blocks 0..255: scan role — 2 batch rows per block, 101 sequential steps.
// Blocks 256..511: copy role — contiguous float2 loads AND stores (lane stride 8B,
//   512B/instr; round-2's float4-load variant made stores stride-16B interleaved,
//   halving write efficiency -> 1.67 TB/s measured). 4 independent loads in flight
//   per iteration via the i / i+half split: 12 waves x 4 x 512B ≈ 24.6 KB/CU in
//   flight -> latency-hiding ceiling ~16 TB/s >> HBM.
__global__ __launch_bounds__(768) void k_scan(
    const float* __restrict__ gx, const float* __restrict__ W_hh,
    const float* __restrict__ b_hh, const float* __restrict__ hidden,
    float* __restrict__ ct,
    const float* __restrict__ src0, const float* __restrict__ src1,
    float2* __restrict__ d0, float2* __restrict__ d1) {
  int tid = threadIdx.x;
  if (blockIdx.x >= 256) {
    const float2* S0 = (const float2*)src0;
    const float2* S1 = (const float2*)src1;
    const size_t half = NPASS / 4;        // 8,388,608 float2 per half-tensor
    const size_t stride = 256ull * 768;
    for (size_t i = (size_t)(blockIdx.x - 256) * 768 + tid; i < half; i += stride) {
      float2 a = S0[i];
      float2 b2 = S0[i + half];
      float2 c = S1[i];
      float2 d = S1[i + half];
      d0[i] = a;
      d0[i + half] = b2;
      d1[i] = c;
      d1[i + half] = d;
    }
    return;
  }
  __shared__ float hs[2][128];
  __shared__ float ghp[2][2][384];  // [row][k-half][g]
  int b0 = blockIdx.x * 2;
  int g = tid % 384, kh = tid / 384;
  float4 w[16];
  const float4* wp = (const float4*)(W_hh + g * 128 + kh * 64);
#pragma unroll
  for (int i = 0; i < 16; i++) w[i] = wp[i];
  if (tid < 256) {
    int r = tid >> 7, k = tid & 127;
    hs[r][k] = hidden[(b0 + r) * 128 + k];
  }
  __syncthreads();
  for (int t = 0; t < 101; t++) {
    const float4* h0 = (const float4*)&hs[0][kh * 64];
    const float4* h1 = (const float4*)&hs[1][kh * 64];
    float a0 = 0.f, a1 = 0.f;
#pragma unroll
    for (int i = 0; i < 16; i++) {
      float4 wv = w[i], x0 = h0[i], x1 = h1[i];
      a0 += wv.x * x0.x + wv.y * x0.y + wv.z * x0.z + wv.w * x0.w;
      a1 += wv.x * x1.x + wv.y * x1.y + wv.z * x1.z + wv.w * x1.w;
    }
    ghp[0][kh][g] = a0;
    ghp[1][kh][g] = a1;
    __syncthreads();
    if (tid < 256) {
      int r = tid >> 7, k = tid & 127;
      const float* gxb = gx + (size_t)t * (512 * 384) + (b0 + r) * 384;
      float xr = gxb[k], xz = gxb[128 + k], xn = gxb[256 + k];
      float hr = ghp[r][0][k] + ghp[r][1][k] + b_hh[k];
      float hz = ghp[r][0][128 + k] + ghp[r][1][128 + k] + b_hh[128 + k];
      float hn = ghp[r][0][256 + k] + ghp[r][1][256 + k] + b_hh[256 + k];
      float rr = 1.f / (1.f + __expf(-(xr + hr)));
      float zz = 1.f / (1.f + __expf(-(xz + hz)));
      float nn = tanhf(xn + rr * hn);
      hs[r][k] = (1.f - zz) * nn + zz * hs[r][k];
    }
    __syncthreads();
  }
  if (tid < 256) {
    int r = tid >> 7, k = tid & 127;
    ct[(b0 + r) * 128 + k] = hs[r][k];
  }
}

// enc[f][b][k] = zq[b][k][101+f]  (LDS bounce to coalesce both sides)
__global__ __launch_bounds__(256) void k_enc(const float* __restrict__ zq,
                                             float* __restrict__ enc) {
  __shared__ float tile[256][17];
  int b = blockIdx.x, tid = threadIdx.x;
  const float* zb = zq + (size_t)b * 65536;
  for (int pass = 0; pass < 16; pass++) {
    int idx = pass * 256 + tid;
    int k = idx >> 4, f = idx & 15;
    tile[k][f] = zb[k * 256 + 101 + f];
  }
  __syncthreads();
  for (int f = 0; f < 16; f++)
    enc[(size_t)f * 131072 + b * 256 + tid] = tile[tid][f];
}

// pred[f][c][k] = Wk_b[f][k] + sum_h Wkt[f][h][k] * ct[c][h]
__global__ __launch_bounds__(256) void k_pred(
    const float* __restrict__ Wkt, const float* __restrict__ Wk_b,
    const float* __restrict__ ct, float* __restrict__ pred) {
  __shared__ float cts[32][128];
  int f = blockIdx.x, c0 = blockIdx.y * 32;
  int tid = threadIdx.x;  // = k
  for (int pass = 0; pass < 16; pass++) {
    int idx = pass * 256 + tid;
    int cc = idx >> 7, h = idx & 127;
    cts[cc][h] = ct[(c0 + cc) * 128 + h];
  }
  __syncthreads();
  float acc[32];
#pragma unroll
  for (int i = 0; i < 32; i++) acc[i] = 0.f;
  const float* wb = Wkt + (size_t)f * 32768 + tid;
  for (int h = 0; h < 128; h += 4) {
    float w0 = wb[(h + 0) * 256], w1 = wb[(h + 1) * 256];
    float w2 = wb[(h + 2) * 256], w3 = wb[(h + 3) * 256];
#pragma unroll
    for (int cc = 0; cc < 32; cc++) {
      float4 cv = *(const float4*)&cts[cc][h];
      acc[cc] += w0 * cv.x + w1 * cv.y + w2 * cv.z + w3 * cv.w;
    }
  }
  float bias = Wk_b[f * 256 + tid];
#pragma unroll
  for (int cc = 0; cc < 32; cc++)
    pred[((size_t)f * 512 + c0 + cc) * 256 + tid] = acc[cc] + bias;
}

// totals[f][b][c] = sum_k enc[f][b][k] * pred[f][c][k]; 64x64 tiles, K=256
__global__ __launch_bounds__(256) void k_totals(
    const float* __restrict__ enc, const float* __restrict__ pred,
    float* __restrict__ tot) {
  __shared__ float As[32][68];
  __shared__ float Bs[32][68];
  int f = blockIdx.z, b0 = blockIdx.y * 64, c0 = blockIdx.x * 64;
  int tid = threadIdx.x;
  int tx = tid & 15, ty = tid >> 4;
  float acc[4][4];
#pragma unroll
  for (int i = 0; i < 4; i++)
#pragma unroll
    for (int j = 0; j < 4; j++) acc[i][j] = 0.f;
  const float* Ab = enc + (size_t)f * 131072;
  const float* Bb = pred + (size_t)f * 131072;
  int lr = tid >> 3;        // 0..31
  int lc = (tid & 7) * 4;   // k sub-offset
  for (int kc = 0; kc < 8; kc++) {
    int k0 = kc * 32;
    __syncthreads();
    float4 av0 = *(const float4*)&Ab[(b0 + lr) * 256 + k0 + lc];
    float4 av1 = *(const float4*)&Ab[(b0 + 32 + lr) * 256 + k0 + lc];
    float4 bv0 = *(const float4*)&Bb[(c0 + lr) * 256 + k0 + lc];
    float4 bv1 = *(const float4*)&Bb[(c0 + 32 + lr) * 256 + k0 + lc];
    As[lc + 0][lr] = av0.x; As[lc + 1][lr] = av0.y;
    As[lc + 2][lr] = av0.z; As[lc + 3][lr] = av0.w;
    As[lc + 0][lr + 32] = av1.x; As[lc + 1][lr + 32] = av1.y;
    As[lc + 2][lr + 32] = av1.z; As[lc + 3][lr + 32] = av1.w;
    Bs[lc + 0][lr] = bv0.x; Bs[lc + 1][lr] = bv0.y;
    Bs[lc + 2][lr] = bv0.z; Bs[lc + 3][lr] = bv0.w;
    Bs[lc + 0][lr + 32] = bv1.x; Bs[lc + 1][lr + 32] = bv1.y;
    Bs[lc + 2][lr + 32] = bv1.z; Bs[lc + 3][lr + 32] = bv1.w;
    __syncthreads();
#pragma unroll
    for (int kk = 0; kk < 32; kk++) {
      float4 a = *(const float4*)&As[kk][ty * 4];
      float4 bq = *(const float4*)&Bs[kk][tx * 4];
      acc[0][0] += a.x * bq.x; acc[0][1] += a.x * bq.y;
      acc[0][2] += a.x * bq.z; acc[0][3] += a.x * bq.w;
      acc[1][0] += a.y * bq.x; acc[1][1] += a.y * bq.y;
      acc[1][2] += a.y * bq.z; acc[1][3] += a.y * bq.w;
      acc[2][0] += a.z * bq.x; acc[2][1] += a.z * bq.y;
      acc[2][2] += a.z * bq.z; acc[2][3] += a.z * bq.w;
      acc[3][0] += a.w * bq.x; acc[3][1] += a.w * bq.y;
      acc[3][2] += a.w * bq.z; acc[3][3] += a.w * bq.w;
    }
  }
#pragma unroll
  for (int i = 0; i < 4; i++) {
    float4 v = make_float4(acc[i][0], acc[i][1], acc[i][2], acc[i][3]);
    *(float4*)&tot[(size_t)f * 262144 + (b0 + ty * 4 + i) * 512 + c0 + tx * 4] = v;
  }
}

// per-row logsumexp + (diag - lse); one wave per (f,b) row
__global__ __launch_bounds__(64) void k_lse(const float* __restrict__ tot,
                                            float* __restrict__ lse,
                                            float* __restrict__ dml) {
  int row = blockIdx.x;  // f*512 + b
  int b = row & 511;
  int lane = threadIdx.x;
  const float* tr = tot + (size_t)row * 512;
  float v[8];
  float mx = -1e30f;
#pragma unroll
  for (int i = 0; i < 8; i++) { v[i] = tr[i * 64 + lane]; mx = fmaxf(mx, v[i]); }
#pragma unroll
  for (int s = 32; s > 0; s >>= 1) mx = fmaxf(mx, __shfl_xor(mx, s));
  float sum = 0.f;
#pragma unroll
  for (int i = 0; i < 8; i++) sum += __expf(v[i] - mx);
#pragma unroll
  for (int s = 32; s > 0; s >>= 1) sum += __shfl_xor(sum, s);
  if (lane == 0) {
    float l = __logf(sum) + mx;
    lse[row] = l;
    dml[row] = tr[b] - l;
  }
}

// accuracy: one wave per column c; shuffle argmax with first-max tie-break.
// (old version: 8 blocks x 64 thr, 512 serial strided loads each = 3% occupancy sleeper)
__global__ __launch_bounds__(64) void k_acc(const float* __restrict__ tot,
                                            const float* __restrict__ lse,
                                            int* __restrict__ cnt) {
  int c = blockIdx.x;
  int lane = threadIdx.x;
  const float* t15 = tot + (size_t)15 * 262144;
  const float* l15 = lse + 15 * 512;
  float best = -1e30f;
  int bi = 1 << 30;
  for (int b = lane; b < 512; b += 64) {
    float v = t15[(size_t)b * 512 + c] - l15[b];
    if (v > best) { best = v; bi = b; }  // strict > keeps lowest b within lane
  }
  for (int s = 32; s > 0; s >>= 1) {
    float ov = __shfl_xor(best, s);
    int oi = __shfl_xor(bi, s);
    if (ov > best || (ov == best && oi < bi)) { best = ov; bi = oi; }
  }
  if (lane == 0 && bi == c) atomicAdd(cnt, 1);
}

__global__ __launch_bounds__(256) void k_fin(const float* __restrict__ dml,
                                             const int* __restrict__ cnt,
                                             float* __restrict__ out) {
  __shared__ float red[256];
  int tid = threadIdx.x;
  float s = 0.f;
  for (int i = tid; i < 8192; i += 256) s += dml[i];
  red[tid] = s;
  __syncthreads();
  for (int st = 128; st > 0; st >>= 1) {
    if (tid < st) red[tid] += red[tid + st];
    __syncthreads();
  }
  if (tid == 0) {
    out[1] = -red[0] / 8192.f;            // nce
    out[0] = (float)(*cnt) / 512.f;       // accuracy
  }
}

extern "C" void kernel_launch(void* const* d_in, const int* in_sizes, int n_in,
                              void* d_out, int out_size, void* d_ws, size_t ws_size,
                              hipStream_t stream) {
  const float* zq   = (const float*)d_in[0];   // z_q_x_st
  const float* ze   = (const float*)d_in[1];   // z_e_x (passthrough)
  const float* zqx  = (const float*)d_in[2];   // z_q_x (passthrough)
  const float* hid  = (const float*)d_in[3];   // hidden (1,B,KH)
  const float* W_ih = (const float*)d_in[4];
  const float* W_hh = (const float*)d_in[5];
  const float* b_ih = (const float*)d_in[6];
  const float* b_hh = (const float*)d_in[7];
  const float* Wk_w = (const float*)d_in[8];
  const float* Wk_b = (const float*)d_in[9];
  // d_in[10] = p_sample (always 100 per setup_inputs; T=101 baked in)
  float* out = (float*)d_out;
  float* ws  = (float*)d_ws;   // needs ~116 MB

  k_transpose<<<2048, 256, 0, stream>>>(W_ih, Wk_w, ws + OFF_WT, ws + OFF_WKT,
                                        (int*)(ws + OFF_CNT));
  k_gx<<<512, 768, 0, stream>>>(zq, ws + OFF_WT, b_ih, ws + OFF_GX);
  // scan (blocks 0..255) + passthrough copy (blocks 256..511) fused:
  // copy soaks the HBM bandwidth the barrier-bound scan leaves idle.
  k_scan<<<512, 768, 0, stream>>>(ws + OFF_GX, W_hh, b_hh, hid, ws + OFF_CT,
                                  ze, zqx,
                                  (float2*)(out + 2), (float2*)(out + 2 + NPASS));
  k_enc<<<512, 256, 0, stream>>>(zq, ws + OFF_ENC);
  k_pred<<<dim3(16, 16), 256, 0, stream>>>(ws + OFF_WKT, Wk_b, ws + OFF_CT, ws + OFF_PRED);
  k_totals<<<dim3(8, 8, 16), 256, 0, stream>>>(ws + OFF_ENC, ws + OFF_PRED, ws + OFF_TOT);
  k_lse<<<8192, 64, 0, stream>>>(ws + OFF_TOT, ws + OFF_LSE, ws + OFF_DML);
  k_acc<<<512, 64, 0, stream>>>(ws + OFF_TOT, ws + OFF_LSE, (int*)(ws + OFF_CNT));
  k_fin<<<1, 256, 0, stream>>>(ws + OFF_DML, (const int*)(ws + OFF_CNT), out);
}

// Round 7
// 912.463 us; speedup vs baseline: 1.0759x; 1.0011x over previous
//
#include <hip/hip_runtime.h>
#include <math.h>

// Problem constants (p_sample=100 fixed by setup_inputs -> T = 101)
#define NB_B   512
#define NK     256
#define NKH    128
#define NG3    384
#define NT     101
#define NF     16
#define NPASS  (512ull*256*256)   // 33,554,432 elements per passthrough tensor

// ---- workspace layout (float offsets) ----
#define OFF_GX   0ull
#define N_GX     (512ull*101*384)        // 19,857,408
#define OFF_CT   (OFF_GX + N_GX)         // c_t: 512*128
#define OFF_ENC  (OFF_CT + 512ull*128)   // enc: 16*512*256
#define OFF_PRED (OFF_ENC + 16ull*512*256)
#define OFF_TOT  (OFF_PRED + 16ull*512*256)  // totals: 16*512*512
#define OFF_LSE  (OFF_TOT + 16ull*512*512)   // 8192
#define OFF_DML  (OFF_LSE + 8192ull)         // 8192 (diag - lse per row)
#define OFF_WT   (OFF_DML + 8192ull)         // W_ih^T: 256*384
#define OFF_WKT  (OFF_WT + 384ull*256)       // Wk_w transposed: 16*128*256
#define OFF_CNT  (OFF_WKT + 16ull*128*256)   // 1 int (correct count)
// total ~115.8 MB of d_ws

// Transpose W_ih -> Wt[k][g], Wk_w[f][k][h] -> Wkt[f][h][k]; also zero cnt.
__global__ __launch_bounds__(256) void k_transpose(
    const float* __restrict__ W_ih, const float* __restrict__ Wk_w,
    float* __restrict__ Wt, float* __restrict__ Wkt, int* __restrict__ cnt) {
  int idx = blockIdx.x * 256 + threadIdx.x;
  if (idx == 0) *cnt = 0;
  if (idx < 384 * 256) {
    int g = idx % 384, k = idx / 384;
    Wt[idx] = W_ih[g * 256 + k];
  }
  if (idx < 16 * 128 * 256) {
    int k = idx & 255, h = (idx >> 8) & 127, f = idx >> 15;
    Wkt[idx] = Wk_w[(f * 256 + k) * 128 + h];
  }
}

// gx[t][b][g] = b_ih[g] (+ b_hh[g] for r,z gates) + sum_k zq[b][k][t] * W_ih[g][k]
// b_hh fold: r/z gates are additive (xr + hr + b_hh_r), so b_hh[0..255] moves here.
// n-gate's b_hh[256..383] is multiplied by r in the GRU -> stays in k_scan.
__global__ __launch_bounds__(768) void k_gx(
    const float* __restrict__ zq, const float* __restrict__ Wt,
    const float* __restrict__ b_ih, const float* __restrict__ b_hh,
    float* __restrict__ gx) {
  __shared__ float Xs[32][104];      // 13,312 B
  __shared__ float Ws[32 * 384];     // 49,152 B  (total 62,464 B < 64 KB)
  int b = blockIdx.x;
  int tid = threadIdx.x;
  int q = tid % 96;                  // g-quad: g0 = 4q
  int tt = tid / 96;                 // 0..7 -> t0 = 13*tt
  int g0 = q * 4;
  int t0 = tt * 13;
  int lane = tid & 63, wid = tid >> 6;  // 12 waves
  float acc[4][13];
#pragma unroll
  for (int i = 0; i < 4; i++)
#pragma unroll
    for (int j = 0; j < 13; j++) acc[i][j] = 0.f;
  const float* zb = zq + (size_t)b * 65536;
  for (int kc = 0; kc < 8; kc++) {
    __syncthreads();
    for (int k = wid; k < 32; k += 12) {
      int kk = kc * 32 + k;
      Xs[k][lane] = zb[kk * 256 + lane];
      int t1 = 64 + lane;
      if (t1 < 104) Xs[k][t1] = (t1 < 101) ? zb[kk * 256 + t1] : 0.f;
    }
    {
      const float4* wsrc = (const float4*)(Wt + (size_t)kc * 32 * 384);
      float4* wdst = (float4*)Ws;
      for (int i = tid; i < 3072; i += 768) wdst[i] = wsrc[i];
    }
    __syncthreads();
    for (int k = 0; k < 32; k++) {
      float4 w = *(const float4*)&Ws[k * 384 + g0];
      const float* xr = &Xs[k][t0];
#pragma unroll
      for (int j = 0; j < 13; j++) {
        float x = xr[j];
        acc[0][j] += w.x * x;
        acc[1][j] += w.y * x;
        acc[2][j] += w.z * x;
        acc[3][j] += w.w * x;
      }
    }
  }
  float4 bias = *(const float4*)&b_ih[g0];
  if (g0 + 3 < 256) {   // quads never straddle 256 (g0 multiple of 4)
    bias.x += b_hh[g0 + 0]; bias.y += b_hh[g0 + 1];
    bias.z += b_hh[g0 + 2]; bias.w += b_hh[g0 + 3];
  }
#pragma unroll
  for (int j = 0; j < 13; j++) {
    int t = t0 + j;
    if (t < 101) {
      float4 v = make_float4(acc[0][j] + bias.x, acc[1][j] + bias.y,
                             acc[2][j] + bias.z, acc[3][j] + bias.w);
      *(float4*)&gx[(size_t)t * (512 * 384) + b * 384 + g0] = v;
    }
  }
}

// GRU scan + passthrough copy, wave-specialized in ONE 1024-thread block.
//   waves 0-11 (tid<768): scan. thread=(kh=tid/384, g=tid%384).
//     W_hh row half held in 64 VGPRs (launch_bounds(1024,4) -> 128-VGPR budget,
//     no rematerialization). h broadcast via v_readlane from 2 lane-resident
//     regs -> LDS pipe idle; inner loop = 64 x {2 readlane + 2 FMA} (VALU).
//     gx for step t+1 prefetched into regs during phase 1 (hides L3 latency).
//   waves 12-15 (tid>=768): copy role. 5 x 512B units per step, issued in
//     phase 1 (~1000 cyc at HBM pace, hidden under the ~1536-cyc gh phase).
//     Barriers are shared textually -> arrival counts match by construction.
__global__ __launch_bounds__(1024, 4) void k_scan(
    const float* __restrict__ gx, const float* __restrict__ W_hh,
    const float* __restrict__ b_hh, const float* __restrict__ hidden,
    float* __restrict__ ct,
    const float* __restrict__ src0, const float* __restrict__ src1,
    float2* __restrict__ d0, float2* __restrict__ d1) {
  __shared__ float hs[2][128];
  __shared__ float ghp[2][2][384];  // [row][kh][g]
  int tid = threadIdx.x;
  int b0 = blockIdx.x * 2;
  bool copy_role = (tid >= 768);

  // ---- scan setup ----
  int kh = tid / 384;        // waves 0-5: kh=0, waves 6-11: kh=1 (uniform per wave)
  int g = tid % 384;
  int lane = tid & 63;
  float w[64];
  float cxr = 0.f, cxz = 0.f, cxn = 0.f, nxr = 0.f, nxz = 0.f, nxn = 0.f;
  float bhn = 0.f;
  // ---- copy setup ----
  const float2* S0 = (const float2*)src0;
  const float2* S1 = (const float2*)src1;
  int c = tid - 768;                          // 0..255
  size_t sbase = (size_t)blockIdx.x * 65536;  // per-tensor float2 slice base
  int p = 0;                                  // units copied (512 total/thread)

  if (!copy_role) {
    const float* wp = W_hh + g * 128 + kh * 64;
#pragma unroll
    for (int i = 0; i < 16; i++) {
      float4 v = *(const float4*)(wp + 4 * i);
      w[4 * i + 0] = v.x; w[4 * i + 1] = v.y;
      w[4 * i + 2] = v.z; w[4 * i + 3] = v.w;
    }
    if (tid < 256) {
      int r = tid >> 7, k = tid & 127;
      hs[r][k] = hidden[(b0 + r) * 128 + k];
      bhn = b_hh[256 + k];
      const float* gxb = gx + (b0 + r) * 384;   // t = 0
      cxr = gxb[k]; cxz = gxb[128 + k]; cxn = gxb[256 + k];
    }
  }
  __syncthreads();

  for (int t = 0; t < 101; t++) {
    // ---------- phase 1: gh = W_hh . h  (scan) | 5 copy units (copy) ----------
    if (!copy_role) {
      float hr0 = hs[0][kh * 64 + lane];
      float hr1 = hs[1][kh * 64 + lane];
      float a0 = 0.f, a1 = 0.f;
#pragma unroll
      for (int j = 0; j < 64; j++) {
        float h0 = __int_as_float(__builtin_amdgcn_readlane(__float_as_int(hr0), j));
        float h1 = __int_as_float(__builtin_amdgcn_readlane(__float_as_int(hr1), j));
        a0 = fmaf(w[j], h0, a0);
        a1 = fmaf(w[j], h1, a1);
      }
      ghp[0][kh][g] = a0;
      ghp[1][kh][g] = a1;
      if (tid < 256 && t < 100) {   // prefetch next step's gx
        int r = tid >> 7, k = tid & 127;
        const float* gxb = gx + (size_t)(t + 1) * (512 * 384) + (b0 + r) * 384;
        nxr = gxb[k]; nxz = gxb[128 + k]; nxn = gxb[256 + k];
      }
    } else {
      // 5 units: u = p..p+4; tensor = u&1, slice idx = (u>>1)*256 + c
#pragma unroll
      for (int uu = 0; uu < 5; uu++) {
        int u = p + uu;
        size_t idx = sbase + (size_t)(u >> 1) * 256 + c;
        if (u & 1) d1[idx] = S1[idx];
        else       d0[idx] = S0[idx];
      }
      p += 5;
    }
    __syncthreads();
    // ---------- phase 2: gate update (256 scan threads) ----------
    if (!copy_role && tid < 256) {
      int r = tid >> 7, k = tid & 127;
      float hrr = ghp[r][0][k] + ghp[r][1][k];
      float hzz = ghp[r][0][128 + k] + ghp[r][1][128 + k];
      float hnn = ghp[r][0][256 + k] + ghp[r][1][256 + k] + bhn;
      float rr = 1.f / (1.f + __expf(-(cxr + hrr)));
      float zz = 1.f / (1.f + __expf(-(cxz + hzz)));
      float nn = tanhf(cxn + rr * hnn);
      hs[r][k] = (1.f - zz) * nn + zz * hs[r][k];
      cxr = nxr; cxz = nxz; cxn = nxn;
    }
    __syncthreads();
  }

  if (!copy_role && tid < 256) {
    int r = tid >> 7, k = tid & 127;
    ct[(b0 + r) * 128 + k] = hs[r][k];
  }
  if (copy_role) {   // tail: 512 - 505 = 7 units
    for (; p < 512; p++) {
      size_t idx = sbase + (size_t)(p >> 1) * 256 + c;
      if (p & 1) d1[idx] = S1[idx];
      else       d0[idx] = S0[idx];
    }
  }
}

// enc[f][b][k] = zq[b][k][101+f]  (LDS bounce to coalesce both sides)
__global__ __launch_bounds__(256) void k_enc(const float* __restrict__ zq,
                                             float* __restrict__ enc) {
  __shared__ float tile[256][17];
  int b = blockIdx.x, tid = threadIdx.x;
  const float* zb = zq + (size_t)b * 65536;
  for (int pass = 0; pass < 16; pass++) {
    int idx = pass * 256 + tid;
    int k = idx >> 4, f = idx & 15;
    tile[k][f] = zb[k * 256 + 101 + f];
  }
  __syncthreads();
  for (int f = 0; f < 16; f++)
    enc[(size_t)f * 131072 + b * 256 + tid] = tile[tid][f];
}

// pred[f][c][k] = Wk_b[f][k] + sum_h Wkt[f][h][k] * ct[c][h]
__global__ __launch_bounds__(256) void k_pred(
    const float* __restrict__ Wkt, const float* __restrict__ Wk_b,
    const float* __restrict__ ct, float* __restrict__ pred) {
  __shared__ float cts[32][128];
  int f = blockIdx.x, c0 = blockIdx.y * 32;
  int tid = threadIdx.x;  // = k
  for (int pass = 0; pass < 16; pass++) {
    int idx = pass * 256 + tid;
    int cc = idx >> 7, h = idx & 127;
    cts[cc][h] = ct[(c0 + cc) * 128 + h];
  }
  __syncthreads();
  float acc[32];
#pragma unroll
  for (int i = 0; i < 32; i++) acc[i] = 0.f;
  const float* wb = Wkt + (size_t)f * 32768 + tid;
  for (int h = 0; h < 128; h += 4) {
    float w0 = wb[(h + 0) * 256], w1 = wb[(h + 1) * 256];
    float w2 = wb[(h + 2) * 256], w3 = wb[(h + 3) * 256];
#pragma unroll
    for (int cc = 0; cc < 32; cc++) {
      float4 cv = *(const float4*)&cts[cc][h];
      acc[cc] += w0 * cv.x + w1 * cv.y + w2 * cv.z + w3 * cv.w;
    }
  }
  float bias = Wk_b[f * 256 + tid];
#pragma unroll
  for (int cc = 0; cc < 32; cc++)
    pred[((size_t)f * 512 + c0 + cc) * 256 + tid] = acc[cc] + bias;
}

// totals[f][b][c] = sum_k enc[f][b][k] * pred[f][c][k]; 64x64 tiles, K=256
__global__ __launch_bounds__(256) void k_totals(
    const float* __restrict__ enc, const float* __restrict__ pred,
    float* __restrict__ tot) {
  __shared__ float As[32][68];
  __shared__ float Bs[32][68];
  int f = blockIdx.z, b0 = blockIdx.y * 64, c0 = blockIdx.x * 64;
  int tid = threadIdx.x;
  int tx = tid & 15, ty = tid >> 4;
  float acc[4][4];
#pragma unroll
  for (int i = 0; i < 4; i++)
#pragma unroll
    for (int j = 0; j < 4; j++) acc[i][j] = 0.f;
  const float* Ab = enc + (size_t)f * 131072;
  const float* Bb = pred + (size_t)f * 131072;
  int lr = tid >> 3;        // 0..31
  int lc = (tid & 7) * 4;   // k sub-offset
  for (int kc = 0; kc < 8; kc++) {
    int k0 = kc * 32;
    __syncthreads();
    float4 av0 = *(const float4*)&Ab[(b0 + lr) * 256 + k0 + lc];
    float4 av1 = *(const float4*)&Ab[(b0 + 32 + lr) * 256 + k0 + lc];
    float4 bv0 = *(const float4*)&Bb[(c0 + lr) * 256 + k0 + lc];
    float4 bv1 = *(const float4*)&Bb[(c0 + 32 + lr) * 256 + k0 + lc];
    As[lc + 0][lr] = av0.x; As[lc + 1][lr] = av0.y;
    As[lc + 2][lr] = av0.z; As[lc + 3][lr] = av0.w;
    As[lc + 0][lr + 32] = av1.x; As[lc + 1][lr + 32] = av1.y;
    As[lc + 2][lr + 32] = av1.z; As[lc + 3][lr + 32] = av1.w;
    Bs[lc + 0][lr] = bv0.x; Bs[lc + 1][lr] = bv0.y;
    Bs[lc + 2][lr] = bv0.z; Bs[lc + 3][lr] = bv0.w;
    Bs[lc + 0][lr + 32] = bv1.x; Bs[lc + 1][lr + 32] = bv1.y;
    Bs[lc + 2][lr + 32] = bv1.z; Bs[lc + 3][lr + 32] = bv1.w;
    __syncthreads();
#pragma unroll
    for (int kk = 0; kk < 32; kk++) {
      float4 a = *(const float4*)&As[kk][ty * 4];
      float4 bq = *(const float4*)&Bs[kk][tx * 4];
      acc[0][0] += a.x * bq.x; acc[0][1] += a.x * bq.y;
      acc[0][2] += a.x * bq.z; acc[0][3] += a.x * bq.w;
      acc[1][0] += a.y * bq.x; acc[1][1] += a.y * bq.y;
      acc[1][2] += a.y * bq.z; acc[1][3] += a.y * bq.w;
      acc[2][0] += a.z * bq.x; acc[2][1] += a.z * bq.y;
      acc[2][2] += a.z * bq.z; acc[2][3] += a.z * bq.w;
      acc[3][0] += a.w * bq.x; acc[3][1] += a.w * bq.y;
      acc[3][2] += a.w * bq.z; acc[3][3] += a.w * bq.w;
    }
  }
#pragma unroll
  for (int i = 0; i < 4; i++) {
    float4 v = make_float4(acc[i][0], acc[i][1], acc[i][2], acc[i][3]);
    *(float4*)&tot[(size_t)f * 262144 + (b0 + ty * 4 + i) * 512 + c0 + tx * 4] = v;
  }
}

// per-row logsumexp + (diag - lse); one wave per (f,b) row
__global__ __launch_bounds__(64) void k_lse(const float* __restrict__ tot,
                                            float* __restrict__ lse,
                                            float* __restrict__ dml) {
  int row = blockIdx.x;  // f*512 + b
  int b = row & 511;
  int lane = threadIdx.x;
  const float* tr = tot + (size_t)row * 512;
  float v[8];
  float mx = -1e30f;
#pragma unroll
  for (int i = 0; i < 8; i++) { v[i] = tr[i * 64 + lane]; mx = fmaxf(mx, v[i]); }
#pragma unroll
  for (int s = 32; s > 0; s >>= 1) mx = fmaxf(mx, __shfl_xor(mx, s));
  float sum = 0.f;
#pragma unroll
  for (int i = 0; i < 8; i++) sum += __expf(v[i] - mx);
#pragma unroll
  for (int s = 32; s > 0; s >>= 1) sum += __shfl_xor(sum, s);
  if (lane == 0) {
    float l = __logf(sum) + mx;
    lse[row] = l;
    dml[row] = tr[b] - l;
  }
}

// accuracy: one wave per column c; shuffle argmax with first-max tie-break.
__global__ __launch_bounds__(64) void k_acc(const float* __restrict__ tot,
                                            const float* __restrict__ lse,
                                            int* __restrict__ cnt) {
  int c = blockIdx.x;
  int lane = threadIdx.x;
  const float* t15 = tot + (size_t)15 * 262144;
  const float* l15 = lse + 15 * 512;
  float best = -1e30f;
  int bi = 1 << 30;
  for (int b = lane; b < 512; b += 64) {
    float v = t15[(size_t)b * 512 + c] - l15[b];
    if (v > best) { best = v; bi = b; }  // strict > keeps lowest b within lane
  }
  for (int s = 32; s > 0; s >>= 1) {
    float ov = __shfl_xor(best, s);
    int oi = __shfl_xor(bi, s);
    if (ov > best || (ov == best && oi < bi)) { best = ov; bi = oi; }
  }
  if (lane == 0 && bi == c) atomicAdd(cnt, 1);
}

__global__ __launch_bounds__(256) void k_fin(const float* __restrict__ dml,
                                             const int* __restrict__ cnt,
                                             float* __restrict__ out) {
  __shared__ float red[256];
  int tid = threadIdx.x;
  float s = 0.f;
  for (int i = tid; i < 8192; i += 256) s += dml[i];
  red[tid] = s;
  __syncthreads();
  for (int st = 128; st > 0; st >>= 1) {
    if (tid < st) red[tid] += red[tid + st];
    __syncthreads();
  }
  if (tid == 0) {
    out[1] = -red[0] / 8192.f;            // nce
    out[0] = (float)(*cnt) / 512.f;       // accuracy
  }
}

extern "C" void kernel_launch(void* const* d_in, const int* in_sizes, int n_in,
                              void* d_out, int out_size, void* d_ws, size_t ws_size,
                              hipStream_t stream) {
  const float* zq   = (const float*)d_in[0];   // z_q_x_st
  const float* ze   = (const float*)d_in[1];   // z_e_x (passthrough)
  const float* zqx  = (const float*)d_in[2];   // z_q_x (passthrough)
  const float* hid  = (const float*)d_in[3];   // hidden (1,B,KH)
  const float* W_ih = (const float*)d_in[4];
  const float* W_hh = (const float*)d_in[5];
  const float* b_ih = (const float*)d_in[6];
  const float* b_hh = (const float*)d_in[7];
  const float* Wk_w = (const float*)d_in[8];
  const float* Wk_b = (const float*)d_in[9];
  // d_in[10] = p_sample (always 100 per setup_inputs; T=101 baked in)
  float* out = (float*)d_out;
  float* ws  = (float*)d_ws;   // needs ~116 MB

  k_transpose<<<2048, 256, 0, stream>>>(W_ih, Wk_w, ws + OFF_WT, ws + OFF_WKT,
                                        (int*)(ws + OFF_CNT));
  k_gx<<<512, 768, 0, stream>>>(zq, ws + OFF_WT, b_ih, b_hh, ws + OFF_GX);
  // scan (12 waves) + passthrough copy (4 waves) wave-specialized per block;
  // 256 blocks x 1024 threads = 1 block/CU, copy hidden under gh compute.
  k_scan<<<256, 1024, 0, stream>>>(ws + OFF_GX, W_hh, b_hh, hid, ws + OFF_CT,
                                   ze, zqx,
                                   (float2*)(out + 2), (float2*)(out + 2 + NPASS));
  k_enc<<<512, 256, 0, stream>>>(zq, ws + OFF_ENC);
  k_pred<<<dim3(16, 16), 256, 0, stream>>>(ws + OFF_WKT, Wk_b, ws + OFF_CT, ws + OFF_PRED);
  k_totals<<<dim3(8, 8, 16), 256, 0, stream>>>(ws + OFF_ENC, ws + OFF_PRED, ws + OFF_TOT);
  k_lse<<<8192, 64, 0, stream>>>(ws + OFF_TOT, ws + OFF_LSE, ws + OFF_DML);
  k_acc<<<512, 64, 0, stream>>>(ws + OFF_TOT, ws + OFF_LSE, (int*)(ws + OFF_CNT));
  k_fin<<<1, 256, 0, stream>>>(ws + OFF_DML, (const int*)(ws + OFF_CNT), out);
}